// Round 6
// baseline (349.417 us; speedup 1.0000x reference)
//
#include <hip/hip_runtime.h>
#include <hip/hip_bf16.h>

typedef __attribute__((ext_vector_type(4))) float f32x4;
typedef __attribute__((ext_vector_type(8))) short short8;
typedef unsigned short u16;

__device__ inline float bf2f(u16 u) {
    unsigned int x = ((unsigned int)u) << 16;
    return __builtin_bit_cast(float, x);
}
__device__ inline u16 f2bf(float f) {
    unsigned int x = __builtin_bit_cast(unsigned int, f);
    unsigned int r = (x + 0x7FFFu + ((x >> 16) & 1u)) >> 16;
    return (u16)r;
}

__device__ inline int edge_at(const void* edges, int flag64, long long idx) {
    if (flag64) return (int)((const long long*)edges)[idx];
    return ((const int*)edges)[idx];
}

// ---------------- probe: int64 vs int32 edge_index ----------------
__global__ void probe_kernel(const void* edges, int n, int* flag) {
    if (threadIdx.x == 0 && blockIdx.x == 0) {
        const long long* p = (const long long*)edges;
        int ok = 1;
        for (int i = 0; i < 64; ++i) {
            long long v = p[i];
            if (v < 0 || v >= n) { ok = 0; break; }
        }
        *flag = ok;
    }
}

// ---------------- CSR build ----------------
__global__ void hist_kernel(const void* edges, const int* flag, int E, int* deg) {
    int f = *flag;
    for (long long i = blockIdx.x * blockDim.x + threadIdx.x; i < E;
         i += (long long)gridDim.x * blockDim.x) {
        int dst = edge_at(edges, f, (long long)E + i);
        atomicAdd(&deg[dst], 1);
    }
}

__global__ void scan1_kernel(const int* deg, int* incl, int* bsum, int n) {
    __shared__ int s[256];
    int i = blockIdx.x * 256 + threadIdx.x;
    int v = (i < n) ? deg[i] : 0;
    s[threadIdx.x] = v;
    __syncthreads();
    for (int d = 1; d < 256; d <<= 1) {
        int t = (threadIdx.x >= d) ? s[threadIdx.x - d] : 0;
        __syncthreads();
        s[threadIdx.x] += t;
        __syncthreads();
    }
    if (i < n) incl[i] = s[threadIdx.x];
    if (threadIdx.x == 255) bsum[blockIdx.x] = s[255];
}

__global__ void scan2_kernel(const int* bsum, int* boff, int nb) {
    __shared__ int s[512];
    int t = threadIdx.x;
    int v = (t < nb) ? bsum[t] : 0;
    s[t] = v;
    __syncthreads();
    for (int d = 1; d < 512; d <<= 1) {
        int u = (t >= d) ? s[t - d] : 0;
        __syncthreads();
        s[t] += u;
        __syncthreads();
    }
    boff[t] = s[t] - v;  // exclusive
}

__global__ void scan3_kernel(const int* incl, const int* deg, const int* boff,
                             int* offs, int* cursor, int n, int E) {
    int i = blockIdx.x * 256 + threadIdx.x;
    if (i < n) {
        int o = boff[blockIdx.x] + incl[i] - deg[i];
        offs[i] = o;
        cursor[i] = o;
    }
    if (i == 0) offs[n] = E;
}

__global__ void scatter_kernel(const void* edges, const int* flag, int E,
                               int* cursor, int* nbr) {
    int f = *flag;
    for (long long i = blockIdx.x * blockDim.x + threadIdx.x; i < E;
         i += (long long)gridDim.x * blockDim.x) {
        int src = edge_at(edges, f, i);
        int dst = edge_at(edges, f, (long long)E + i);
        int pos = atomicAdd(&cursor[dst], 1);
        nbr[pos] = src;
    }
}

// ---------------- conversions ----------------
__global__ void cvt_x_kernel(const float* __restrict__ x, u16* __restrict__ out, long long n4) {
    long long i = blockIdx.x * blockDim.x + threadIdx.x;
    if (i >= n4) return;
    float4 v = ((const float4*)x)[i];
    ushort4 o;
    o.x = f2bf(v.x); o.y = f2bf(v.y); o.z = f2bf(v.z); o.w = f2bf(v.w);
    ((ushort4*)out)[i] = o;
}

// all 6 weight matrices in ONE kernel: Wt[m*K + k] = bf16(W[k*M + m])
struct WcvtArgs {
    const float* w[6];
    u16* o[6];
    int K[6], M[6];
    int pre[7];  // prefix of sizes
};
__global__ void cvt_w_all_kernel(WcvtArgs a) {
    int i = blockIdx.x * blockDim.x + threadIdx.x;
    if (i >= a.pre[6]) return;
    int mi = 0;
#pragma unroll
    for (int q = 1; q < 6; ++q) mi += (i >= a.pre[q]);
    int loc = i - a.pre[mi];
    int K = a.K[mi], M = a.M[mi];
    int m = loc / K, k = loc % K;
    a.o[mi][loc] = f2bf(a.w[mi][(size_t)k * M + m]);
}

// ---------------- aggregation: h = (x + sum_nbr x[nbr]) [+bias, relu] ----------------
// 256-thread blocks (4 waves). NPW nodes per wave:
//   NPW=1: d=256, 64 lanes x ushort4 (8B) per row
//   NPW=2: d=128, half-wave (32 lanes) x ushort4 per row, 2 nodes/wave
// Batch-8 gather: all 8 neighbor rows in flight before accumulation.
template <int NPW, bool BR>
__global__ __launch_bounds__(256) void agg_kernel(
    const u16* __restrict__ X, u16* __restrict__ H,
    const int* __restrict__ offs, const int* __restrict__ nbr,
    const float* __restrict__ bias, int n) {
    constexpr int D = (NPW == 1) ? 256 : 128;
    const int tid = threadIdx.x;
    const int wid = tid >> 6;
    const int lane = tid & 63;
    const int sub = (NPW == 2) ? (lane >> 5) : 0;
    const int sl = (NPW == 2) ? (lane & 31) : lane;
    const int node = blockIdx.x * (4 * NPW) + wid * NPW + sub;
    if (node >= n) return;

    const int s = offs[node], e = offs[node + 1];
    const int cnt = min(e - s, 8);

    // self row + up to 8 neighbor indices, then 8 row loads all in flight
    ushort4 sv = *(const ushort4*)(X + (size_t)node * D + sl * 4);
    int idx[8];
#pragma unroll
    for (int q = 0; q < 8; ++q)
        if (q < cnt) idx[q] = nbr[s + q];
    ushort4 rv[8];
#pragma unroll
    for (int q = 0; q < 8; ++q)
        if (q < cnt) rv[q] = *(const ushort4*)(X + (size_t)idx[q] * D + sl * 4);

    float acc[4] = {bf2f(sv.x), bf2f(sv.y), bf2f(sv.z), bf2f(sv.w)};
#pragma unroll
    for (int q = 0; q < 8; ++q)
        if (q < cnt) {
            acc[0] += bf2f(rv[q].x); acc[1] += bf2f(rv[q].y);
            acc[2] += bf2f(rv[q].z); acc[3] += bf2f(rv[q].w);
        }

    // tail (deg > 8), batch of 4
    int j = s + 8;
    while (__any(j < e)) {
        const int c2 = e - j;
        ushort4 tv[4];
        int ti[4];
#pragma unroll
        for (int q = 0; q < 4; ++q)
            if (q < c2) ti[q] = nbr[j + q];
#pragma unroll
        for (int q = 0; q < 4; ++q)
            if (q < c2) tv[q] = *(const ushort4*)(X + (size_t)ti[q] * D + sl * 4);
#pragma unroll
        for (int q = 0; q < 4; ++q)
            if (q < c2) {
                acc[0] += bf2f(tv[q].x); acc[1] += bf2f(tv[q].y);
                acc[2] += bf2f(tv[q].z); acc[3] += bf2f(tv[q].w);
            }
        j += 4;
    }

    if (BR) {
        float4 b4 = *(const float4*)&bias[sl * 4];
        acc[0] = fmaxf(acc[0] + b4.x, 0.f);
        acc[1] = fmaxf(acc[1] + b4.y, 0.f);
        acc[2] = fmaxf(acc[2] + b4.z, 0.f);
        acc[3] = fmaxf(acc[3] + b4.w, 0.f);
    }
    ushort4 o;
    o.x = f2bf(acc[0]); o.y = f2bf(acc[1]); o.z = f2bf(acc[2]); o.w = f2bf(acc[3]);
    *(ushort4*)(H + (size_t)node * D + sl * 4) = o;
}

// ---------------- MFMA helpers ----------------
__device__ inline f32x4 mfma16(short8 a, short8 b, f32x4 c) {
    return __builtin_amdgcn_mfma_f32_16x16x32_bf16(a, b, c, 0, 0, 0);
}

// ---------------- persistent fused MLP (2 GEMMs), bf16 out ----------------
template <int K1, int M1, int M2>
__global__ __launch_bounds__(512, 2) void mlp_kernel(
    const u16* __restrict__ H, const u16* __restrict__ W1t, const float* __restrict__ b1,
    const u16* __restrict__ W2t, const float* __restrict__ b2,
    u16* __restrict__ outp, int Nrows, int ntiles) {
    constexpr int S1 = K1 + 8;
    constexpr int S2 = M1 + 16;
    constexpr int SO = M2 + 16;
    constexpr int NK1 = K1 / 32, NK2 = M1 / 32;
    constexpr int CW1 = M1 / 128, CW2 = M2 / 128;
    constexpr size_t LA = (size_t)64 * S1 * 2;
    constexpr size_t LT = (size_t)64 * S2 * 2;
    extern __shared__ char smem[];
    u16* bufA = (u16*)smem;
    u16* bufT = (u16*)(smem + LA);
    u16* bufO = (u16*)(smem + LA + LT);

    const int tid = threadIdx.x;
    const int lane = tid & 63;
    const int wid = tid >> 6;
    const int fl = lane & 15;
    const int kg = lane >> 4;
    const int rb = kg << 2;

    const int ws1 = wid * (M1 / 8);
    const int ws2 = wid * (M2 / 8);
    short8 w1f[CW1][NK1];
    short8 w2f[CW2][NK2];
    float bias1[CW1], bias2[CW2];
#pragma unroll
    for (int c = 0; c < CW1; ++c) {
        const u16* wp = W1t + (size_t)(ws1 + c * 16 + fl) * K1 + kg * 8;
        bias1[c] = b1[ws1 + c * 16 + fl];
#pragma unroll
        for (int kk = 0; kk < NK1; ++kk) w1f[c][kk] = *(const short8*)(wp + kk * 32);
    }
#pragma unroll
    for (int c = 0; c < CW2; ++c) {
        const u16* wp = W2t + (size_t)(ws2 + c * 16 + fl) * M1 + kg * 8;
        bias2[c] = b2[ws2 + c * 16 + fl];
#pragma unroll
        for (int kk = 0; kk < NK2; ++kk) w2f[c][kk] = *(const short8*)(wp + kk * 32);
    }

    constexpr int TPR = K1 / 8;
    constexpr int RPI = 512 / TPR;
    constexpr int NPASS = 64 / RPI;
    const int srow = tid / TPR;
    const int sce = (tid % TPR) * 8;

    uint4 apf[NPASS];
    auto load_tile = [&](int t) {
#pragma unroll
        for (int p = 0; p < NPASS; ++p) {
            apf[p] = make_uint4(0, 0, 0, 0);
            if (t < ntiles) {
                const int r = t * 64 + p * RPI + srow;
                if (r < Nrows) apf[p] = *(const uint4*)(H + (size_t)r * K1 + sce);
            }
        }
    };

    load_tile(blockIdx.x);

    for (int t = blockIdx.x; t < ntiles; t += gridDim.x) {
        const int r0 = t * 64;
#pragma unroll
        for (int p = 0; p < NPASS; ++p)
            *(uint4*)&bufA[(p * RPI + srow) * S1 + sce] = apf[p];
        __syncthreads();  // B1: A ready

        load_tile(t + gridDim.x);  // prefetch next tile under GEMM1

        f32x4 acc[4][CW1];
#pragma unroll
        for (int m = 0; m < 4; ++m)
#pragma unroll
            for (int c = 0; c < CW1; ++c) acc[m][c] = (f32x4){0.f, 0.f, 0.f, 0.f};
#pragma unroll
        for (int kk = 0; kk < NK1; ++kk) {
            short8 a[4];
#pragma unroll
            for (int m = 0; m < 4; ++m)
                a[m] = *(const short8*)&bufA[(m * 16 + fl) * S1 + kk * 32 + kg * 8];
#pragma unroll
            for (int c = 0; c < CW1; ++c)
#pragma unroll
                for (int m = 0; m < 4; ++m) acc[m][c] = mfma16(a[m], w1f[c][kk], acc[m][c]);
        }

#pragma unroll
        for (int c = 0; c < CW1; ++c) {
            const int col = ws1 + c * 16 + fl;
#pragma unroll
            for (int m = 0; m < 4; ++m)
#pragma unroll
                for (int j = 0; j < 4; ++j) {
                    float v = fmaxf(acc[m][c][j] + bias1[c], 0.f);
                    bufT[(m * 16 + rb + j) * S2 + col] = f2bf(v);
                }
        }
        __syncthreads();  // B2: T ready

        f32x4 acc2[4][CW2];
#pragma unroll
        for (int m = 0; m < 4; ++m)
#pragma unroll
            for (int c = 0; c < CW2; ++c) acc2[m][c] = (f32x4){0.f, 0.f, 0.f, 0.f};
#pragma unroll
        for (int kk = 0; kk < NK2; ++kk) {
            short8 a[4];
#pragma unroll
            for (int m = 0; m < 4; ++m)
                a[m] = *(const short8*)&bufT[(m * 16 + fl) * S2 + kk * 32 + kg * 8];
#pragma unroll
            for (int c = 0; c < CW2; ++c)
#pragma unroll
                for (int m = 0; m < 4; ++m) acc2[m][c] = mfma16(a[m], w2f[c][kk], acc2[m][c]);
        }

#pragma unroll
        for (int c = 0; c < CW2; ++c) {
            const int col = ws2 + c * 16 + fl;
#pragma unroll
            for (int m = 0; m < 4; ++m)
#pragma unroll
                for (int j = 0; j < 4; ++j) {
                    float v = fmaxf(acc2[m][c][j] + bias2[c], 0.f);
                    bufO[(m * 16 + rb + j) * SO + col] = f2bf(v);
                }
        }
        __syncthreads();  // B3: Out staged

        {
            constexpr int ROWB = M2 * 2;
            constexpr int TPRO = ROWB / 16;
            constexpr int RPIO = 512 / TPRO;
            const int orow = tid / TPRO;
            const int ocb = (tid % TPRO) * 16;
#pragma unroll
            for (int p = 0; p < 64 / RPIO; ++p) {
                const int row = p * RPIO + orow;
                if (r0 + row < Nrows) {
                    uint4 v = *(const uint4*)((char*)bufO + (size_t)row * SO * 2 + ocb);
                    *(uint4*)((char*)outp + (size_t)(r0 + row) * ROWB + ocb) = v;
                }
            }
        }
    }
}

// ---------------- persistent single GEMM: out = [relu](A@W [+b]) ----------------
template <int K, int M, bool BR, bool F32OUT>
__global__ __launch_bounds__(512, 4) void gemm1_kernel(
    const u16* __restrict__ H, const u16* __restrict__ Wt,
    const float* __restrict__ bias, void* __restrict__ outp,
    int Nrows, int ntiles) {
    constexpr int S1 = K + 8;
    constexpr int SO = F32OUT ? (M + 4) : (M + 16);
    constexpr int OB = F32OUT ? 4 : 2;
    constexpr int NK = K / 32;
    constexpr int CW = M / 128;
    constexpr size_t LA = (size_t)64 * S1 * 2;
    extern __shared__ char smem[];
    u16* bufA = (u16*)smem;
    char* bufO = smem + LA;

    const int tid = threadIdx.x;
    const int lane = tid & 63;
    const int wid = tid >> 6;
    const int fl = lane & 15;
    const int kg = lane >> 4;
    const int rb = kg << 2;

    const int ws = wid * (M / 8);
    short8 wf[CW][NK];
    float bs[CW];
#pragma unroll
    for (int c = 0; c < CW; ++c) {
        const u16* wp = Wt + (size_t)(ws + c * 16 + fl) * K + kg * 8;
        bs[c] = BR ? bias[ws + c * 16 + fl] : 0.f;
#pragma unroll
        for (int kk = 0; kk < NK; ++kk) wf[c][kk] = *(const short8*)(wp + kk * 32);
    }

    constexpr int TPR = K / 8;
    constexpr int RPI = 512 / TPR;
    constexpr int NPASS = 64 / RPI;
    const int srow = tid / TPR;
    const int sce = (tid % TPR) * 8;

    uint4 apf[NPASS];
    auto load_tile = [&](int t) {
#pragma unroll
        for (int p = 0; p < NPASS; ++p) {
            apf[p] = make_uint4(0, 0, 0, 0);
            if (t < ntiles) {
                const int r = t * 64 + p * RPI + srow;
                if (r < Nrows) apf[p] = *(const uint4*)(H + (size_t)r * K + sce);
            }
        }
    };

    load_tile(blockIdx.x);

    for (int t = blockIdx.x; t < ntiles; t += gridDim.x) {
        const int r0 = t * 64;
#pragma unroll
        for (int p = 0; p < NPASS; ++p)
            *(uint4*)&bufA[(p * RPI + srow) * S1 + sce] = apf[p];
        __syncthreads();  // B1: A ready

        load_tile(t + gridDim.x);

        f32x4 acc[4][CW];
#pragma unroll
        for (int m = 0; m < 4; ++m)
#pragma unroll
            for (int c = 0; c < CW; ++c) acc[m][c] = (f32x4){0.f, 0.f, 0.f, 0.f};
#pragma unroll
        for (int kk = 0; kk < NK; ++kk) {
            short8 a[4];
#pragma unroll
            for (int m = 0; m < 4; ++m)
                a[m] = *(const short8*)&bufA[(m * 16 + fl) * S1 + kk * 32 + kg * 8];
#pragma unroll
            for (int c = 0; c < CW; ++c)
#pragma unroll
                for (int m = 0; m < 4; ++m) acc[m][c] = mfma16(a[m], wf[c][kk], acc[m][c]);
        }

#pragma unroll
        for (int c = 0; c < CW; ++c) {
            const int col = ws + c * 16 + fl;
#pragma unroll
            for (int m = 0; m < 4; ++m)
#pragma unroll
                for (int j = 0; j < 4; ++j) {
                    float v = acc[m][c][j];
                    if (BR) v = fmaxf(v + bs[c], 0.f);
                    const int row = m * 16 + rb + j;
                    if (F32OUT)
                        ((float*)bufO)[row * SO + col] = v;
                    else
                        ((u16*)bufO)[row * SO + col] = f2bf(v);
                }
        }
        __syncthreads();  // B2: Out staged

        {
            constexpr int ROWB = M * OB;
            constexpr int TPRO = ROWB / 16;
            constexpr int RPIO = 512 / TPRO;
            const int orow = tid / TPRO;
            const int ocb = (tid % TPRO) * 16;
#pragma unroll
            for (int p = 0; p < 64 / RPIO; ++p) {
                const int row = p * RPIO + orow;
                if (r0 + row < Nrows) {
                    uint4 v = *(const uint4*)(bufO + (size_t)row * SO * OB + ocb);
                    *(uint4*)((char*)outp + (size_t)(r0 + row) * ROWB + ocb) = v;
                }
            }
        }
    }
}

// ---------------- host ----------------
extern "C" void kernel_launch(void* const* d_in, const int* in_sizes, int n_in,
                              void* d_out, int out_size, void* d_ws, size_t ws_size,
                              hipStream_t stream) {
    const int IN = 128, HID = 256, OUTD = 128;
    const int N = in_sizes[0] / IN;
    const int E = in_sizes[1] / 2;

    const float* x = (const float*)d_in[0];
    const void* edges = d_in[1];
    const float* w0a = (const float*)d_in[2];  const float* b0a = (const float*)d_in[3];
    const float* w0b = (const float*)d_in[4];  const float* b0b = (const float*)d_in[5];
    const float* w1a = (const float*)d_in[6];  const float* b1a = (const float*)d_in[7];
    const float* w1b = (const float*)d_in[8];  const float* b1b = (const float*)d_in[9];
    const float* w2a = (const float*)d_in[10]; const float* b2a = (const float*)d_in[11];
    const float* w2b = (const float*)d_in[12]; const float* b2b = (const float*)d_in[13];

    char* ws = (char*)d_ws;
    size_t off = 0;
    auto alloc = [&](size_t b) { size_t o = off; off = (off + b + 255) & ~(size_t)255; return o; };
    int* flag   = (int*)(ws + alloc(4));
    int* deg    = (int*)(ws + alloc((size_t)N * 4));
    int* incl   = (int*)(ws + alloc((size_t)N * 4));
    int* bsum   = (int*)(ws + alloc(512 * 4));
    int* boff   = (int*)(ws + alloc(512 * 4));
    int* offs   = (int*)(ws + alloc((size_t)(N + 1) * 4));
    int* cursor = (int*)(ws + alloc((size_t)N * 4));
    int* nbr    = (int*)(ws + alloc((size_t)E * 4));
    u16* wt0a = (u16*)(ws + alloc((size_t)IN * HID * 2));
    u16* wt0b = (u16*)(ws + alloc((size_t)HID * HID * 2));
    u16* wt1a = (u16*)(ws + alloc((size_t)HID * HID * 2));
    u16* wt1b = (u16*)(ws + alloc((size_t)HID * HID * 2));
    u16* wt2a = (u16*)(ws + alloc((size_t)HID * OUTD * 2));
    u16* wt2b = (u16*)(ws + alloc((size_t)OUTD * OUTD * 2));
    u16* Pa = (u16*)(ws + alloc((size_t)N * HID * 2));
    u16* Pb = (u16*)(ws + alloc((size_t)N * HID * 2));

    // CSR build
    probe_kernel<<<1, 64, 0, stream>>>(edges, N, flag);
    hipMemsetAsync(deg, 0, (size_t)N * 4, stream);
    hist_kernel<<<2048, 256, 0, stream>>>(edges, flag, E, deg);
    int nb1 = (N + 255) / 256;
    scan1_kernel<<<nb1, 256, 0, stream>>>(deg, incl, bsum, N);
    scan2_kernel<<<1, 512, 0, stream>>>(bsum, boff, nb1);
    scan3_kernel<<<nb1, 256, 0, stream>>>(incl, deg, boff, offs, cursor, N, E);
    scatter_kernel<<<2048, 256, 0, stream>>>(edges, flag, E, cursor, nbr);

    // input conversion + all weight conversions in one kernel
    long long n4 = (long long)N * IN / 4;
    cvt_x_kernel<<<(int)((n4 + 255) / 256), 256, 0, stream>>>(x, Pa, n4);
    {
        WcvtArgs a;
        a.w[0] = w0a; a.o[0] = wt0a; a.K[0] = IN;   a.M[0] = HID;
        a.w[1] = w0b; a.o[1] = wt0b; a.K[1] = HID;  a.M[1] = HID;
        a.w[2] = w1a; a.o[2] = wt1a; a.K[2] = HID;  a.M[2] = HID;
        a.w[3] = w1b; a.o[3] = wt1b; a.K[3] = HID;  a.M[3] = HID;
        a.w[4] = w2a; a.o[4] = wt2a; a.K[4] = HID;  a.M[4] = OUTD;
        a.w[5] = w2b; a.o[5] = wt2b; a.K[5] = OUTD; a.M[5] = OUTD;
        a.pre[0] = 0;
        for (int q = 0; q < 6; ++q) a.pre[q + 1] = a.pre[q] + a.K[q] * a.M[q];
        cvt_w_all_kernel<<<(a.pre[6] + 255) / 256, 256, 0, stream>>>(a);
    }

    const int ntiles = (N + 63) / 64;
    const int pgrid = ntiles < 256 ? ntiles : 256;
    const int ggrid = ntiles < 512 ? ntiles : 512;

    const size_t mlp_lds0 = (size_t)64 * (128 + 8) * 2 + (size_t)64 * (256 + 16) * 2 * 2;
    const size_t mlp_lds1 = (size_t)64 * (256 + 8) * 2 + (size_t)64 * (256 + 16) * 2 * 2;
    const size_t pre_lds  = (size_t)64 * (256 + 8) * 2 + (size_t)64 * (128 + 16) * 2;
    const size_t fin_lds  = (size_t)64 * (128 + 8) * 2 + (size_t)64 * (128 + 4) * 4;

    // layer 0: agg d=128 (2 nodes/wave), MLP 128->256->256
    agg_kernel<2, false><<<(N + 7) / 8, 256, 0, stream>>>(Pa, Pb, offs, nbr, nullptr, N);
    mlp_kernel<128, 256, 256><<<pgrid, 512, mlp_lds0, stream>>>(Pb, wt0a, b0a, wt0b, b0b, Pa, N, ntiles);
    // layer 1: agg d=256 (1 node/wave), MLP 256->256->256
    agg_kernel<1, false><<<(N + 3) / 4, 256, 0, stream>>>(Pa, Pb, offs, nbr, nullptr, N);
    mlp_kernel<256, 256, 256><<<pgrid, 512, mlp_lds1, stream>>>(Pb, wt1a, b1a, wt1b, b1b, Pa, N, ntiles);
    // layer 2 (restructured): y = x@W2a; t = relu(y + agg(y) + b2a); out = relu(t@W2b + b2b)
    gemm1_kernel<256, 128, false, false><<<ggrid, 512, pre_lds, stream>>>(Pa, wt2a, nullptr, Pb, N, ntiles);
    agg_kernel<2, true><<<(N + 7) / 8, 256, 0, stream>>>(Pb, Pa, offs, nbr, b2a, N);
    gemm1_kernel<128, 128, true, true><<<ggrid, 512, fin_lds, stream>>>(Pa, wt2b, b2b, d_out, N, ntiles);
}

// Round 7
// 329.433 us; speedup vs baseline: 1.0607x; 1.0607x over previous
//
#include <hip/hip_runtime.h>
#include <hip/hip_bf16.h>

typedef __attribute__((ext_vector_type(4))) float f32x4;
typedef __attribute__((ext_vector_type(8))) short short8;
typedef unsigned short u16;

__device__ inline float bf2f(u16 u) {
    unsigned int x = ((unsigned int)u) << 16;
    return __builtin_bit_cast(float, x);
}
__device__ inline u16 f2bf(float f) {
    unsigned int x = __builtin_bit_cast(unsigned int, f);
    unsigned int r = (x + 0x7FFFu + ((x >> 16) & 1u)) >> 16;
    return (u16)r;
}

__device__ inline int edge_at(const void* edges, int flag64, long long idx) {
    if (flag64) return (int)((const long long*)edges)[idx];
    return ((const int*)edges)[idx];
}

// ---------------- probe: int64 vs int32 edge_index ----------------
__global__ void probe_kernel(const void* edges, int n, int* flag) {
    if (threadIdx.x == 0 && blockIdx.x == 0) {
        const long long* p = (const long long*)edges;
        int ok = 1;
        for (int i = 0; i < 64; ++i) {
            long long v = p[i];
            if (v < 0 || v >= n) { ok = 0; break; }
        }
        *flag = ok;
    }
}

// ---------------- CSR build ----------------
__global__ void hist_kernel(const void* edges, const int* flag, int E, int* deg) {
    int f = *flag;
    for (long long i = blockIdx.x * blockDim.x + threadIdx.x; i < E;
         i += (long long)gridDim.x * blockDim.x) {
        int dst = edge_at(edges, f, (long long)E + i);
        atomicAdd(&deg[dst], 1);
    }
}

__global__ void scan1_kernel(const int* deg, int* incl, int* bsum, int n) {
    __shared__ int s[256];
    int i = blockIdx.x * 256 + threadIdx.x;
    int v = (i < n) ? deg[i] : 0;
    s[threadIdx.x] = v;
    __syncthreads();
    for (int d = 1; d < 256; d <<= 1) {
        int t = (threadIdx.x >= d) ? s[threadIdx.x - d] : 0;
        __syncthreads();
        s[threadIdx.x] += t;
        __syncthreads();
    }
    if (i < n) incl[i] = s[threadIdx.x];
    if (threadIdx.x == 255) bsum[blockIdx.x] = s[255];
}

__global__ void scan2_kernel(const int* bsum, int* boff, int nb) {
    __shared__ int s[512];
    int t = threadIdx.x;
    int v = (t < nb) ? bsum[t] : 0;
    s[t] = v;
    __syncthreads();
    for (int d = 1; d < 512; d <<= 1) {
        int u = (t >= d) ? s[t - d] : 0;
        __syncthreads();
        s[t] += u;
        __syncthreads();
    }
    boff[t] = s[t] - v;  // exclusive
}

__global__ void scan3_kernel(const int* incl, const int* deg, const int* boff,
                             int* offs, int* cursor, int n, int E) {
    int i = blockIdx.x * 256 + threadIdx.x;
    if (i < n) {
        int o = boff[blockIdx.x] + incl[i] - deg[i];
        offs[i] = o;
        cursor[i] = o;
    }
    if (i == 0) offs[n] = E;
}

__global__ void scatter_kernel(const void* edges, const int* flag, int E,
                               int* cursor, int* nbr) {
    int f = *flag;
    for (long long i = blockIdx.x * blockDim.x + threadIdx.x; i < E;
         i += (long long)gridDim.x * blockDim.x) {
        int src = edge_at(edges, f, i);
        int dst = edge_at(edges, f, (long long)E + i);
        int pos = atomicAdd(&cursor[dst], 1);
        nbr[pos] = src;
    }
}

// ---------------- conversions ----------------
__global__ void cvt_x_kernel(const float* __restrict__ x, u16* __restrict__ out, long long n4) {
    long long i = blockIdx.x * blockDim.x + threadIdx.x;
    if (i >= n4) return;
    float4 v = ((const float4*)x)[i];
    ushort4 o;
    o.x = f2bf(v.x); o.y = f2bf(v.y); o.z = f2bf(v.z); o.w = f2bf(v.w);
    ((ushort4*)out)[i] = o;
}

// all 6 weight matrices in ONE kernel: Wt[m*K + k] = bf16(W[k*M + m])
struct WcvtArgs {
    const float* w[6];
    u16* o[6];
    int K[6], M[6];
    int pre[7];  // prefix of sizes
};
__global__ void cvt_w_all_kernel(WcvtArgs a) {
    int i = blockIdx.x * blockDim.x + threadIdx.x;
    if (i >= a.pre[6]) return;
    int mi = 0;
#pragma unroll
    for (int q = 1; q < 6; ++q) mi += (i >= a.pre[q]);
    int loc = i - a.pre[mi];
    int K = a.K[mi], M = a.M[mi];
    int m = loc / K, k = loc % K;
    a.o[mi][loc] = f2bf(a.w[mi][(size_t)k * M + m]);
}

// ---------------- aggregation: h = (x + sum_nbr x[nbr]) [+bias, relu] ----------------
// 1 wave per block (round-5 proven occupancy profile). LPR lanes per row,
// each lane loads ushort4 (8B): LPR=64 -> d=256 (1 node/wave),
// LPR=32 -> d=128 (2 nodes/wave, 256B rows per half-wave).
// Simple batch-4 gather loop (round-5 winner; no predication overhead).
template <int LPR, bool BR>
__global__ __launch_bounds__(64) void agg_kernel(
    const u16* __restrict__ X, u16* __restrict__ H,
    const int* __restrict__ offs, const int* __restrict__ nbr,
    const float* __restrict__ bias, int n) {
    constexpr int D = LPR * 4;
    constexpr int NPW = 64 / LPR;
    const int lane = threadIdx.x;
    const int sub = (NPW == 2) ? (lane >> 5) : 0;
    const int sl = (NPW == 2) ? (lane & 31) : lane;
    const int node = blockIdx.x * NPW + sub;
    if (node >= n) return;

    ushort4 sv = *(const ushort4*)(X + (size_t)node * D + sl * 4);
    float acc[4] = {bf2f(sv.x), bf2f(sv.y), bf2f(sv.z), bf2f(sv.w)};

    const int s = offs[node], e = offs[node + 1];
    int j = s;
    for (; j + 4 <= e; j += 4) {  // 4 independent row loads in flight
        int n0 = nbr[j], n1 = nbr[j + 1], n2 = nbr[j + 2], n3 = nbr[j + 3];
        ushort4 v0 = *(const ushort4*)(X + (size_t)n0 * D + sl * 4);
        ushort4 v1 = *(const ushort4*)(X + (size_t)n1 * D + sl * 4);
        ushort4 v2 = *(const ushort4*)(X + (size_t)n2 * D + sl * 4);
        ushort4 v3 = *(const ushort4*)(X + (size_t)n3 * D + sl * 4);
        acc[0] += bf2f(v0.x) + bf2f(v1.x) + bf2f(v2.x) + bf2f(v3.x);
        acc[1] += bf2f(v0.y) + bf2f(v1.y) + bf2f(v2.y) + bf2f(v3.y);
        acc[2] += bf2f(v0.z) + bf2f(v1.z) + bf2f(v2.z) + bf2f(v3.z);
        acc[3] += bf2f(v0.w) + bf2f(v1.w) + bf2f(v2.w) + bf2f(v3.w);
    }
    for (; j < e; ++j) {
        int nb = nbr[j];
        ushort4 v = *(const ushort4*)(X + (size_t)nb * D + sl * 4);
        acc[0] += bf2f(v.x); acc[1] += bf2f(v.y);
        acc[2] += bf2f(v.z); acc[3] += bf2f(v.w);
    }

    if (BR) {
        float4 b4 = *(const float4*)&bias[sl * 4];
        acc[0] = fmaxf(acc[0] + b4.x, 0.f);
        acc[1] = fmaxf(acc[1] + b4.y, 0.f);
        acc[2] = fmaxf(acc[2] + b4.z, 0.f);
        acc[3] = fmaxf(acc[3] + b4.w, 0.f);
    }
    ushort4 o;
    o.x = f2bf(acc[0]); o.y = f2bf(acc[1]); o.z = f2bf(acc[2]); o.w = f2bf(acc[3]);
    *(ushort4*)(H + (size_t)node * D + sl * 4) = o;
}

// ---------------- MFMA helpers ----------------
__device__ inline f32x4 mfma16(short8 a, short8 b, f32x4 c) {
    return __builtin_amdgcn_mfma_f32_16x16x32_bf16(a, b, c, 0, 0, 0);
}

// ---------------- persistent fused MLP (2 GEMMs), bf16 out ----------------
template <int K1, int M1, int M2>
__global__ __launch_bounds__(512, 2) void mlp_kernel(
    const u16* __restrict__ H, const u16* __restrict__ W1t, const float* __restrict__ b1,
    const u16* __restrict__ W2t, const float* __restrict__ b2,
    u16* __restrict__ outp, int Nrows, int ntiles) {
    constexpr int S1 = K1 + 8;
    constexpr int S2 = M1 + 16;
    constexpr int SO = M2 + 16;
    constexpr int NK1 = K1 / 32, NK2 = M1 / 32;
    constexpr int CW1 = M1 / 128, CW2 = M2 / 128;
    constexpr size_t LA = (size_t)64 * S1 * 2;
    constexpr size_t LT = (size_t)64 * S2 * 2;
    extern __shared__ char smem[];
    u16* bufA = (u16*)smem;
    u16* bufT = (u16*)(smem + LA);
    u16* bufO = (u16*)(smem + LA + LT);

    const int tid = threadIdx.x;
    const int lane = tid & 63;
    const int wid = tid >> 6;
    const int fl = lane & 15;
    const int kg = lane >> 4;
    const int rb = kg << 2;

    const int ws1 = wid * (M1 / 8);
    const int ws2 = wid * (M2 / 8);
    short8 w1f[CW1][NK1];
    short8 w2f[CW2][NK2];
    float bias1[CW1], bias2[CW2];
#pragma unroll
    for (int c = 0; c < CW1; ++c) {
        const u16* wp = W1t + (size_t)(ws1 + c * 16 + fl) * K1 + kg * 8;
        bias1[c] = b1[ws1 + c * 16 + fl];
#pragma unroll
        for (int kk = 0; kk < NK1; ++kk) w1f[c][kk] = *(const short8*)(wp + kk * 32);
    }
#pragma unroll
    for (int c = 0; c < CW2; ++c) {
        const u16* wp = W2t + (size_t)(ws2 + c * 16 + fl) * M1 + kg * 8;
        bias2[c] = b2[ws2 + c * 16 + fl];
#pragma unroll
        for (int kk = 0; kk < NK2; ++kk) w2f[c][kk] = *(const short8*)(wp + kk * 32);
    }

    constexpr int TPR = K1 / 8;
    constexpr int RPI = 512 / TPR;
    constexpr int NPASS = 64 / RPI;
    const int srow = tid / TPR;
    const int sce = (tid % TPR) * 8;

    uint4 apf[NPASS];
    auto load_tile = [&](int t) {
#pragma unroll
        for (int p = 0; p < NPASS; ++p) {
            apf[p] = make_uint4(0, 0, 0, 0);
            if (t < ntiles) {
                const int r = t * 64 + p * RPI + srow;
                if (r < Nrows) apf[p] = *(const uint4*)(H + (size_t)r * K1 + sce);
            }
        }
    };

    load_tile(blockIdx.x);

    for (int t = blockIdx.x; t < ntiles; t += gridDim.x) {
        const int r0 = t * 64;
#pragma unroll
        for (int p = 0; p < NPASS; ++p)
            *(uint4*)&bufA[(p * RPI + srow) * S1 + sce] = apf[p];
        __syncthreads();  // B1: A ready

        load_tile(t + gridDim.x);  // prefetch next tile under GEMM1

        f32x4 acc[4][CW1];
#pragma unroll
        for (int m = 0; m < 4; ++m)
#pragma unroll
            for (int c = 0; c < CW1; ++c) acc[m][c] = (f32x4){0.f, 0.f, 0.f, 0.f};
#pragma unroll
        for (int kk = 0; kk < NK1; ++kk) {
            short8 a[4];
#pragma unroll
            for (int m = 0; m < 4; ++m)
                a[m] = *(const short8*)&bufA[(m * 16 + fl) * S1 + kk * 32 + kg * 8];
#pragma unroll
            for (int c = 0; c < CW1; ++c)
#pragma unroll
                for (int m = 0; m < 4; ++m) acc[m][c] = mfma16(a[m], w1f[c][kk], acc[m][c]);
        }

#pragma unroll
        for (int c = 0; c < CW1; ++c) {
            const int col = ws1 + c * 16 + fl;
#pragma unroll
            for (int m = 0; m < 4; ++m)
#pragma unroll
                for (int j = 0; j < 4; ++j) {
                    float v = fmaxf(acc[m][c][j] + bias1[c], 0.f);
                    bufT[(m * 16 + rb + j) * S2 + col] = f2bf(v);
                }
        }
        __syncthreads();  // B2: T ready

        f32x4 acc2[4][CW2];
#pragma unroll
        for (int m = 0; m < 4; ++m)
#pragma unroll
            for (int c = 0; c < CW2; ++c) acc2[m][c] = (f32x4){0.f, 0.f, 0.f, 0.f};
#pragma unroll
        for (int kk = 0; kk < NK2; ++kk) {
            short8 a[4];
#pragma unroll
            for (int m = 0; m < 4; ++m)
                a[m] = *(const short8*)&bufT[(m * 16 + fl) * S2 + kk * 32 + kg * 8];
#pragma unroll
            for (int c = 0; c < CW2; ++c)
#pragma unroll
                for (int m = 0; m < 4; ++m) acc2[m][c] = mfma16(a[m], w2f[c][kk], acc2[m][c]);
        }

#pragma unroll
        for (int c = 0; c < CW2; ++c) {
            const int col = ws2 + c * 16 + fl;
#pragma unroll
            for (int m = 0; m < 4; ++m)
#pragma unroll
                for (int j = 0; j < 4; ++j) {
                    float v = fmaxf(acc2[m][c][j] + bias2[c], 0.f);
                    bufO[(m * 16 + rb + j) * SO + col] = f2bf(v);
                }
        }
        __syncthreads();  // B3: Out staged

        {
            constexpr int ROWB = M2 * 2;
            constexpr int TPRO = ROWB / 16;
            constexpr int RPIO = 512 / TPRO;
            const int orow = tid / TPRO;
            const int ocb = (tid % TPRO) * 16;
#pragma unroll
            for (int p = 0; p < 64 / RPIO; ++p) {
                const int row = p * RPIO + orow;
                if (r0 + row < Nrows) {
                    uint4 v = *(const uint4*)((char*)bufO + (size_t)row * SO * 2 + ocb);
                    *(uint4*)((char*)outp + (size_t)(r0 + row) * ROWB + ocb) = v;
                }
            }
        }
    }
}

// ---------------- persistent single GEMM: out = [relu](A@W [+b]) ----------------
template <int K, int M, bool BR, bool F32OUT>
__global__ __launch_bounds__(512, 4) void gemm1_kernel(
    const u16* __restrict__ H, const u16* __restrict__ Wt,
    const float* __restrict__ bias, void* __restrict__ outp,
    int Nrows, int ntiles) {
    constexpr int S1 = K + 8;
    constexpr int SO = F32OUT ? (M + 4) : (M + 16);
    constexpr int OB = F32OUT ? 4 : 2;
    constexpr int NK = K / 32;
    constexpr int CW = M / 128;
    constexpr size_t LA = (size_t)64 * S1 * 2;
    extern __shared__ char smem[];
    u16* bufA = (u16*)smem;
    char* bufO = smem + LA;

    const int tid = threadIdx.x;
    const int lane = tid & 63;
    const int wid = tid >> 6;
    const int fl = lane & 15;
    const int kg = lane >> 4;
    const int rb = kg << 2;

    const int ws = wid * (M / 8);
    short8 wf[CW][NK];
    float bs[CW];
#pragma unroll
    for (int c = 0; c < CW; ++c) {
        const u16* wp = Wt + (size_t)(ws + c * 16 + fl) * K + kg * 8;
        bs[c] = BR ? bias[ws + c * 16 + fl] : 0.f;
#pragma unroll
        for (int kk = 0; kk < NK; ++kk) wf[c][kk] = *(const short8*)(wp + kk * 32);
    }

    constexpr int TPR = K / 8;
    constexpr int RPI = 512 / TPR;
    constexpr int NPASS = 64 / RPI;
    const int srow = tid / TPR;
    const int sce = (tid % TPR) * 8;

    uint4 apf[NPASS];
    auto load_tile = [&](int t) {
#pragma unroll
        for (int p = 0; p < NPASS; ++p) {
            apf[p] = make_uint4(0, 0, 0, 0);
            if (t < ntiles) {
                const int r = t * 64 + p * RPI + srow;
                if (r < Nrows) apf[p] = *(const uint4*)(H + (size_t)r * K + sce);
            }
        }
    };

    load_tile(blockIdx.x);

    for (int t = blockIdx.x; t < ntiles; t += gridDim.x) {
        const int r0 = t * 64;
#pragma unroll
        for (int p = 0; p < NPASS; ++p)
            *(uint4*)&bufA[(p * RPI + srow) * S1 + sce] = apf[p];
        __syncthreads();  // B1: A ready

        load_tile(t + gridDim.x);

        f32x4 acc[4][CW];
#pragma unroll
        for (int m = 0; m < 4; ++m)
#pragma unroll
            for (int c = 0; c < CW; ++c) acc[m][c] = (f32x4){0.f, 0.f, 0.f, 0.f};
#pragma unroll
        for (int kk = 0; kk < NK; ++kk) {
            short8 a[4];
#pragma unroll
            for (int m = 0; m < 4; ++m)
                a[m] = *(const short8*)&bufA[(m * 16 + fl) * S1 + kk * 32 + kg * 8];
#pragma unroll
            for (int c = 0; c < CW; ++c)
#pragma unroll
                for (int m = 0; m < 4; ++m) acc[m][c] = mfma16(a[m], wf[c][kk], acc[m][c]);
        }

#pragma unroll
        for (int c = 0; c < CW; ++c) {
            const int col = ws + c * 16 + fl;
#pragma unroll
            for (int m = 0; m < 4; ++m)
#pragma unroll
                for (int j = 0; j < 4; ++j) {
                    float v = acc[m][c][j];
                    if (BR) v = fmaxf(v + bs[c], 0.f);
                    const int row = m * 16 + rb + j;
                    if (F32OUT)
                        ((float*)bufO)[row * SO + col] = v;
                    else
                        ((u16*)bufO)[row * SO + col] = f2bf(v);
                }
        }
        __syncthreads();  // B2: Out staged

        {
            constexpr int ROWB = M * OB;
            constexpr int TPRO = ROWB / 16;
            constexpr int RPIO = 512 / TPRO;
            const int orow = tid / TPRO;
            const int ocb = (tid % TPRO) * 16;
#pragma unroll
            for (int p = 0; p < 64 / RPIO; ++p) {
                const int row = p * RPIO + orow;
                if (r0 + row < Nrows) {
                    uint4 v = *(const uint4*)(bufO + (size_t)row * SO * OB + ocb);
                    *(uint4*)((char*)outp + (size_t)(r0 + row) * ROWB + ocb) = v;
                }
            }
        }
    }
}

// ---------------- host ----------------
extern "C" void kernel_launch(void* const* d_in, const int* in_sizes, int n_in,
                              void* d_out, int out_size, void* d_ws, size_t ws_size,
                              hipStream_t stream) {
    const int IN = 128, HID = 256, OUTD = 128;
    const int N = in_sizes[0] / IN;
    const int E = in_sizes[1] / 2;

    const float* x = (const float*)d_in[0];
    const void* edges = d_in[1];
    const float* w0a = (const float*)d_in[2];  const float* b0a = (const float*)d_in[3];
    const float* w0b = (const float*)d_in[4];  const float* b0b = (const float*)d_in[5];
    const float* w1a = (const float*)d_in[6];  const float* b1a = (const float*)d_in[7];
    const float* w1b = (const float*)d_in[8];  const float* b1b = (const float*)d_in[9];
    const float* w2a = (const float*)d_in[10]; const float* b2a = (const float*)d_in[11];
    const float* w2b = (const float*)d_in[12]; const float* b2b = (const float*)d_in[13];

    char* ws = (char*)d_ws;
    size_t off = 0;
    auto alloc = [&](size_t b) { size_t o = off; off = (off + b + 255) & ~(size_t)255; return o; };
    int* flag   = (int*)(ws + alloc(4));
    int* deg    = (int*)(ws + alloc((size_t)N * 4));
    int* incl   = (int*)(ws + alloc((size_t)N * 4));
    int* bsum   = (int*)(ws + alloc(512 * 4));
    int* boff   = (int*)(ws + alloc(512 * 4));
    int* offs   = (int*)(ws + alloc((size_t)(N + 1) * 4));
    int* cursor = (int*)(ws + alloc((size_t)N * 4));
    int* nbr    = (int*)(ws + alloc((size_t)E * 4));
    u16* wt0a = (u16*)(ws + alloc((size_t)IN * HID * 2));
    u16* wt0b = (u16*)(ws + alloc((size_t)HID * HID * 2));
    u16* wt1a = (u16*)(ws + alloc((size_t)HID * HID * 2));
    u16* wt1b = (u16*)(ws + alloc((size_t)HID * HID * 2));
    u16* wt2a = (u16*)(ws + alloc((size_t)HID * OUTD * 2));
    u16* wt2b = (u16*)(ws + alloc((size_t)OUTD * OUTD * 2));
    u16* Pa = (u16*)(ws + alloc((size_t)N * HID * 2));
    u16* Pb = (u16*)(ws + alloc((size_t)N * HID * 2));

    // CSR build
    probe_kernel<<<1, 64, 0, stream>>>(edges, N, flag);
    hipMemsetAsync(deg, 0, (size_t)N * 4, stream);
    hist_kernel<<<2048, 256, 0, stream>>>(edges, flag, E, deg);
    int nb1 = (N + 255) / 256;
    scan1_kernel<<<nb1, 256, 0, stream>>>(deg, incl, bsum, N);
    scan2_kernel<<<1, 512, 0, stream>>>(bsum, boff, nb1);
    scan3_kernel<<<nb1, 256, 0, stream>>>(incl, deg, boff, offs, cursor, N, E);
    scatter_kernel<<<2048, 256, 0, stream>>>(edges, flag, E, cursor, nbr);

    // input conversion + all weight conversions in one kernel
    long long n4 = (long long)N * IN / 4;
    cvt_x_kernel<<<(int)((n4 + 255) / 256), 256, 0, stream>>>(x, Pa, n4);
    {
        WcvtArgs a;
        a.w[0] = w0a; a.o[0] = wt0a; a.K[0] = IN;   a.M[0] = HID;
        a.w[1] = w0b; a.o[1] = wt0b; a.K[1] = HID;  a.M[1] = HID;
        a.w[2] = w1a; a.o[2] = wt1a; a.K[2] = HID;  a.M[2] = HID;
        a.w[3] = w1b; a.o[3] = wt1b; a.K[3] = HID;  a.M[3] = HID;
        a.w[4] = w2a; a.o[4] = wt2a; a.K[4] = HID;  a.M[4] = OUTD;
        a.w[5] = w2b; a.o[5] = wt2b; a.K[5] = OUTD; a.M[5] = OUTD;
        a.pre[0] = 0;
        for (int q = 0; q < 6; ++q) a.pre[q + 1] = a.pre[q] + a.K[q] * a.M[q];
        cvt_w_all_kernel<<<(a.pre[6] + 255) / 256, 256, 0, stream>>>(a);
    }

    const int ntiles = (N + 63) / 64;
    const int pgrid = ntiles < 256 ? ntiles : 256;
    const int ggrid = ntiles < 512 ? ntiles : 512;

    const size_t mlp_lds0 = (size_t)64 * (128 + 8) * 2 + (size_t)64 * (256 + 16) * 2 * 2;
    const size_t mlp_lds1 = (size_t)64 * (256 + 8) * 2 + (size_t)64 * (256 + 16) * 2 * 2;
    const size_t pre_lds  = (size_t)64 * (256 + 8) * 2 + (size_t)64 * (128 + 16) * 2;
    const size_t fin_lds  = (size_t)64 * (128 + 8) * 2 + (size_t)64 * (128 + 4) * 4;

    // layer 0: agg d=128 (2 nodes/wave, 8B lanes), MLP 128->256->256
    agg_kernel<32, false><<<(N + 1) / 2, 64, 0, stream>>>(Pa, Pb, offs, nbr, nullptr, N);
    mlp_kernel<128, 256, 256><<<pgrid, 512, mlp_lds0, stream>>>(Pb, wt0a, b0a, wt0b, b0b, Pa, N, ntiles);
    // layer 1: agg d=256 (1 node/wave, round-5 winner), MLP 256->256->256
    agg_kernel<64, false><<<N, 64, 0, stream>>>(Pa, Pb, offs, nbr, nullptr, N);
    mlp_kernel<256, 256, 256><<<pgrid, 512, mlp_lds1, stream>>>(Pb, wt1a, b1a, wt1b, b1b, Pa, N, ntiles);
    // layer 2 (restructured): y = x@W2a; t = relu(y + agg(y) + b2a); out = relu(t@W2b + b2b)
    gemm1_kernel<256, 128, false, false><<<ggrid, 512, pre_lds, stream>>>(Pa, wt2a, nullptr, Pb, N, ntiles);
    agg_kernel<32, true><<<(N + 1) / 2, 64, 0, stream>>>(Pb, Pa, offs, nbr, b2a, N);
    gemm1_kernel<128, 128, true, true><<<ggrid, 512, fin_lds, stream>>>(Pa, wt2b, b2b, d_out, N, ntiles);
}